// Round 1
// baseline (661.959 us; speedup 1.0000x reference)
//
#include <hip/hip_runtime.h>

#define NN 50000
#define NE 600000
#define KF 128      // IN_FEATS == H_FEATS
#define OC1 128
#define OC2 64

// ---------------- degree histogram ----------------
__global__ void deg_kernel(const int* __restrict__ src, const int* __restrict__ dst,
                           float* __restrict__ dout, float* __restrict__ din) {
    int e = blockIdx.x * blockDim.x + threadIdx.x;
    if (e >= NE) return;
    atomicAdd(&dout[src[e]], 1.0f);
    atomicAdd(&din[dst[e]], 1.0f);
}

// v = rsqrt(max(v,1)) over n elements (both norm arrays back-to-back)
__global__ void norm_kernel(float* __restrict__ v, int n) {
    int i = blockIdx.x * blockDim.x + threadIdx.x;
    if (i < n) v[i] = rsqrtf(fmaxf(v[i], 1.0f));
}

// ---------------- edge scatter: agg[dst] += h[src] * nsrc[src] ----------------
__global__ void scatter_kernel(const float* __restrict__ h, const float* __restrict__ nsrc,
                               const int* __restrict__ src, const int* __restrict__ dst,
                               float* __restrict__ agg) {
    int idx = blockIdx.x * blockDim.x + threadIdx.x;   // < NE*KF = 76.8M, fits int32
    if (idx >= NE * KF) return;
    int e = idx >> 7;           // KF = 128
    int f = idx & (KF - 1);
    int s = src[e];
    int d = dst[e];
    atomicAdd(&agg[(size_t)d * KF + f], h[(size_t)s * KF + f] * nsrc[s]);
}

// ---------------- fused GEMM: out[r] = act(ndst[r] * (A[r] @ W) + b) ----------------
// A: [NN, KF]  W: [KF, OC]  b: [OC]  out: [NN, OC]
template <int OC, bool RELU>
__launch_bounds__(256)
__global__ void gemm_kernel(const float* __restrict__ A, const float* __restrict__ W,
                            const float* __restrict__ b, const float* __restrict__ ndst,
                            float* __restrict__ out) {
    constexpr int CG = OC / 4;          // float4 column groups: 32 or 16
    constexpr int RT = 256 / CG;        // concurrent row-threads: 8 or 16
    constexpr int ROWS = 64;            // rows per block
    constexpr int RPT = ROWS / RT;      // rows per thread: 8 or 4
    constexpr int LDA = KF + 4;         // pad to break bank-conflict (132 % 4 == 0 for float4)
    __shared__ float As[ROWS][LDA];

    const int tid = threadIdx.x;
    const int row0 = blockIdx.x * ROWS;

    // cooperative float4 stage of the 64x128 A-tile
    for (int i = tid; i < ROWS * (KF / 4); i += 256) {
        int r = i >> 5;                 // KF/4 == 32
        int c = i & 31;
        float4 v = make_float4(0.f, 0.f, 0.f, 0.f);
        if (row0 + r < NN)
            v = reinterpret_cast<const float4*>(A + (size_t)(row0 + r) * KF)[c];
        reinterpret_cast<float4*>(&As[r][0])[c] = v;
    }
    __syncthreads();

    const int cg = tid % CG;
    const int rt = tid / CG;

    float4 acc[RPT];
#pragma unroll
    for (int i = 0; i < RPT; i++) acc[i] = make_float4(0.f, 0.f, 0.f, 0.f);

#pragma unroll 4
    for (int k = 0; k < KF; k++) {
        float4 w = reinterpret_cast<const float4*>(W + (size_t)k * OC)[cg];
#pragma unroll
        for (int rr = 0; rr < RPT; rr++) {
            float a = As[rt + rr * RT][k];
            acc[rr].x = fmaf(a, w.x, acc[rr].x);
            acc[rr].y = fmaf(a, w.y, acc[rr].y);
            acc[rr].z = fmaf(a, w.z, acc[rr].z);
            acc[rr].w = fmaf(a, w.w, acc[rr].w);
        }
    }

    float4 bias = reinterpret_cast<const float4*>(b)[cg];
#pragma unroll
    for (int rr = 0; rr < RPT; rr++) {
        int r = row0 + rt + rr * RT;
        if (r < NN) {
            float nd = ndst[r];
            float4 o;
            o.x = fmaf(acc[rr].x, nd, bias.x);
            o.y = fmaf(acc[rr].y, nd, bias.y);
            o.z = fmaf(acc[rr].z, nd, bias.z);
            o.w = fmaf(acc[rr].w, nd, bias.w);
            if (RELU) {
                o.x = fmaxf(o.x, 0.f);
                o.y = fmaxf(o.y, 0.f);
                o.z = fmaxf(o.z, 0.f);
                o.w = fmaxf(o.w, 0.f);
            }
            reinterpret_cast<float4*>(out + (size_t)r * OC)[cg] = o;
        }
    }
}

extern "C" void kernel_launch(void* const* d_in, const int* in_sizes, int n_in,
                              void* d_out, int out_size, void* d_ws, size_t ws_size,
                              hipStream_t stream) {
    const float* x  = (const float*)d_in[0];   // [NN, 128]
    const float* W1 = (const float*)d_in[1];   // [128, 128]
    const float* b1 = (const float*)d_in[2];   // [128]
    const float* W2 = (const float*)d_in[3];   // [128, 64]
    const float* b2 = (const float*)d_in[4];   // [64]
    const int*   src = (const int*)d_in[5];    // [NE]
    const int*   dst = (const int*)d_in[6];    // [NE]
    float* out = (float*)d_out;                // [NN, 64]

    float* ws   = (float*)d_ws;
    float* nsrc = ws;                          // NN  (1/sqrt(out_deg))
    float* ndst = ws + NN;                     // NN  (1/sqrt(in_deg))
    float* agg  = ws + 2 * NN;                 // NN*KF
    float* h1   = agg + (size_t)NN * KF;       // NN*KF

    // degrees -> norms
    hipMemsetAsync(nsrc, 0, 2 * NN * sizeof(float), stream);
    deg_kernel<<<(NE + 255) / 256, 256, 0, stream>>>(src, dst, nsrc, ndst);
    norm_kernel<<<(2 * NN + 255) / 256, 256, 0, stream>>>(nsrc, 2 * NN);

    // layer 1: agg = scatter(x * nsrc), h1 = relu(ndst * (agg @ W1) + b1)
    hipMemsetAsync(agg, 0, (size_t)NN * KF * sizeof(float), stream);
    scatter_kernel<<<(NE * KF + 255) / 256, 256, 0, stream>>>(x, nsrc, src, dst, agg);
    gemm_kernel<OC1, true><<<(NN + 63) / 64, 256, 0, stream>>>(agg, W1, b1, ndst, h1);

    // layer 2: agg = scatter(h1 * nsrc), out = ndst * (agg @ W2) + b2
    hipMemsetAsync(agg, 0, (size_t)NN * KF * sizeof(float), stream);
    scatter_kernel<<<(NE * KF + 255) / 256, 256, 0, stream>>>(h1, nsrc, src, dst, agg);
    gemm_kernel<OC2, false><<<(NN + 63) / 64, 256, 0, stream>>>(agg, W2, b2, ndst, out);
}

// Round 2
// 326.614 us; speedup vs baseline: 2.0267x; 2.0267x over previous
//
#include <hip/hip_runtime.h>

#define NN 50000
#define NE 600000
#define KF 128      // IN_FEATS == H_FEATS
#define OC1 128
#define OC2 64

// ---------------- degree histogram (int atomics) ----------------
__global__ void deg_kernel(const int* __restrict__ src, const int* __restrict__ dst,
                           int* __restrict__ deg_o, int* __restrict__ deg_i) {
    int e = blockIdx.x * blockDim.x + threadIdx.x;
    if (e >= NE) return;
    atomicAdd(&deg_o[src[e]], 1);
    atomicAdd(&deg_i[dst[e]], 1);
}

// norms from integer degrees
__global__ void norm_kernel(const int* __restrict__ deg_o, const int* __restrict__ deg_i,
                            float* __restrict__ nsrc, float* __restrict__ ndst) {
    int i = blockIdx.x * blockDim.x + threadIdx.x;
    if (i >= NN) return;
    nsrc[i] = rsqrtf(fmaxf((float)deg_o[i], 1.0f));
    ndst[i] = rsqrtf(fmaxf((float)deg_i[i], 1.0f));
}

// ---------------- single-block exclusive scan of in-degrees -> col_ptr ----------------
#define SCAN_T 1024
__launch_bounds__(SCAN_T)
__global__ void scan_kernel(const int* __restrict__ deg, int* __restrict__ ptr) {
    __shared__ int sums[SCAN_T];
    const int tid = threadIdx.x;
    const int C = (NN + SCAN_T - 1) / SCAN_T;  // 49
    const int lo = tid * C;
    const int hi = min(lo + C, NN);
    int t = 0;
    for (int i = lo; i < hi; i++) t += deg[i];
    sums[tid] = t;
    __syncthreads();
    // Hillis-Steele inclusive scan
    for (int off = 1; off < SCAN_T; off <<= 1) {
        int v = (tid >= off) ? sums[tid - off] : 0;
        __syncthreads();
        sums[tid] += v;
        __syncthreads();
    }
    int run = (tid == 0) ? 0 : sums[tid - 1];
    for (int i = lo; i < hi; i++) { ptr[i] = run; run += deg[i]; }
    if (tid == SCAN_T - 1) ptr[NN] = run;   // == NE
}

__global__ void copy_ptr_kernel(const int* __restrict__ ptr, int* __restrict__ cursor) {
    int i = blockIdx.x * blockDim.x + threadIdx.x;
    if (i < NN) cursor[i] = ptr[i];
}

// fill dst-sorted edge list
__global__ void fill_kernel(const int* __restrict__ src, const int* __restrict__ dst,
                            int* __restrict__ cursor, int* __restrict__ esrc) {
    int e = blockIdx.x * blockDim.x + threadIdx.x;
    if (e >= NE) return;
    int p = atomicAdd(&cursor[dst[e]], 1);
    esrc[p] = src[e];
}

// ---------------- GEMM: g[r] = nsrc[r] * (A[r] @ W) ----------------
// A: [NN, KF]  W: [KF, OC]  g: [NN, OC]
template <int OC>
__launch_bounds__(256)
__global__ void gemm_scale_kernel(const float* __restrict__ A, const float* __restrict__ W,
                                  const float* __restrict__ nsrc, float* __restrict__ g) {
    constexpr int CG = OC / 4;          // float4 column groups: 32 or 16
    constexpr int RT = 256 / CG;        // concurrent row-threads: 8 or 16
    constexpr int ROWS = 64;            // rows per block
    constexpr int RPT = ROWS / RT;      // rows per thread: 8 or 4
    constexpr int LDA = KF + 4;
    __shared__ float As[ROWS][LDA];

    const int tid = threadIdx.x;
    const int row0 = blockIdx.x * ROWS;

    for (int i = tid; i < ROWS * (KF / 4); i += 256) {
        int r = i >> 5;                 // KF/4 == 32
        int c = i & 31;
        float4 v = make_float4(0.f, 0.f, 0.f, 0.f);
        if (row0 + r < NN)
            v = reinterpret_cast<const float4*>(A + (size_t)(row0 + r) * KF)[c];
        reinterpret_cast<float4*>(&As[r][0])[c] = v;
    }
    __syncthreads();

    const int cg = tid % CG;
    const int rt = tid / CG;

    float4 acc[RPT];
#pragma unroll
    for (int i = 0; i < RPT; i++) acc[i] = make_float4(0.f, 0.f, 0.f, 0.f);

#pragma unroll 4
    for (int k = 0; k < KF; k++) {
        float4 w = reinterpret_cast<const float4*>(W + (size_t)k * OC)[cg];
#pragma unroll
        for (int rr = 0; rr < RPT; rr++) {
            float a = As[rt + rr * RT][k];
            acc[rr].x = fmaf(a, w.x, acc[rr].x);
            acc[rr].y = fmaf(a, w.y, acc[rr].y);
            acc[rr].z = fmaf(a, w.z, acc[rr].z);
            acc[rr].w = fmaf(a, w.w, acc[rr].w);
        }
    }

#pragma unroll
    for (int rr = 0; rr < RPT; rr++) {
        int r = row0 + rt + rr * RT;
        if (r < NN) {
            float ns = nsrc[r];
            float4 o = make_float4(acc[rr].x * ns, acc[rr].y * ns,
                                   acc[rr].z * ns, acc[rr].w * ns);
            reinterpret_cast<float4*>(g + (size_t)r * OC)[cg] = o;
        }
    }
}

// ---------------- gather: out[d] = act(ndst[d] * sum_{e in in(d)} g[esrc[e]] + b) ----------------
// one wave per node, block = 4 waves
template <int OC, bool RELU>
__launch_bounds__(256)
__global__ void gather_kernel(const float* __restrict__ g, const int* __restrict__ ptr,
                              const int* __restrict__ esrc, const float* __restrict__ ndst,
                              const float* __restrict__ b, float* __restrict__ out) {
    const int node = blockIdx.x * 4 + (threadIdx.x >> 6);
    if (node >= NN) return;
    const int lane = threadIdx.x & 63;
    const int lo = ptr[node];
    const int hi = ptr[node + 1];
    const float nd = ndst[node];

    if (OC == 128) {
        float2 acc0 = make_float2(0.f, 0.f), acc1 = make_float2(0.f, 0.f);
        int e = lo;
        for (; e + 1 < hi; e += 2) {
            int s0 = esrc[e];
            int s1 = esrc[e + 1];
            float2 v0 = reinterpret_cast<const float2*>(g + (size_t)s0 * OC)[lane];
            float2 v1 = reinterpret_cast<const float2*>(g + (size_t)s1 * OC)[lane];
            acc0.x += v0.x; acc0.y += v0.y;
            acc1.x += v1.x; acc1.y += v1.y;
        }
        if (e < hi) {
            int s0 = esrc[e];
            float2 v0 = reinterpret_cast<const float2*>(g + (size_t)s0 * OC)[lane];
            acc0.x += v0.x; acc0.y += v0.y;
        }
        acc0.x += acc1.x; acc0.y += acc1.y;
        float2 bb = reinterpret_cast<const float2*>(b)[lane];
        float2 o = make_float2(fmaf(acc0.x, nd, bb.x), fmaf(acc0.y, nd, bb.y));
        if (RELU) { o.x = fmaxf(o.x, 0.f); o.y = fmaxf(o.y, 0.f); }
        reinterpret_cast<float2*>(out + (size_t)node * OC)[lane] = o;
    } else {
        float acc0 = 0.f, acc1 = 0.f;
        int e = lo;
        for (; e + 1 < hi; e += 2) {
            int s0 = esrc[e];
            int s1 = esrc[e + 1];
            acc0 += g[(size_t)s0 * OC + lane];
            acc1 += g[(size_t)s1 * OC + lane];
        }
        if (e < hi) acc0 += g[(size_t)esrc[e] * OC + lane];
        acc0 += acc1;
        float o = fmaf(acc0, nd, b[lane]);
        if (RELU) o = fmaxf(o, 0.f);
        out[(size_t)node * OC + lane] = o;
    }
}

extern "C" void kernel_launch(void* const* d_in, const int* in_sizes, int n_in,
                              void* d_out, int out_size, void* d_ws, size_t ws_size,
                              hipStream_t stream) {
    const float* x  = (const float*)d_in[0];   // [NN, 128]
    const float* W1 = (const float*)d_in[1];   // [128, 128]
    const float* b1 = (const float*)d_in[2];   // [128]
    const float* W2 = (const float*)d_in[3];   // [128, 64]
    const float* b2 = (const float*)d_in[4];   // [64]
    const int*   src = (const int*)d_in[5];    // [NE]
    const int*   dst = (const int*)d_in[6];    // [NE]
    float* out = (float*)d_out;                // [NN, 64]

    float* ws   = (float*)d_ws;
    float* nsrc = ws;                          // NN
    float* ndst = nsrc + NN;                   // NN
    float* g    = ndst + NN;                   // NN*128 (reused for layer-2's NN*64)
    float* h1   = g + (size_t)NN * KF;         // NN*128
    int*   deg_o  = (int*)(h1 + (size_t)NN * KF); // NN (reused area ends here)
    int*   deg_i  = deg_o + NN;                // NN
    int*   ptr    = deg_i + NN;                // NN+1
    int*   cursor = ptr + NN + 1;              // NN
    int*   esrc   = cursor + NN;               // NE

    // degrees -> norms, CSC build
    hipMemsetAsync(deg_o, 0, 2 * NN * sizeof(int), stream);
    deg_kernel<<<(NE + 255) / 256, 256, 0, stream>>>(src, dst, deg_o, deg_i);
    norm_kernel<<<(NN + 255) / 256, 256, 0, stream>>>(deg_o, deg_i, nsrc, ndst);
    scan_kernel<<<1, SCAN_T, 0, stream>>>(deg_i, ptr);
    copy_ptr_kernel<<<(NN + 255) / 256, 256, 0, stream>>>(ptr, cursor);
    fill_kernel<<<(NE + 255) / 256, 256, 0, stream>>>(src, dst, cursor, esrc);

    // layer 1: g = nsrc * (x @ W1); h1 = relu(ndst * gather(g) + b1)
    gemm_scale_kernel<OC1><<<(NN + 63) / 64, 256, 0, stream>>>(x, W1, nsrc, g);
    gather_kernel<OC1, true><<<(NN + 3) / 4, 256, 0, stream>>>(g, ptr, esrc, ndst, b1, h1);

    // layer 2: g = nsrc * (h1 @ W2); out = ndst * gather(g) + b2
    gemm_scale_kernel<OC2><<<(NN + 63) / 64, 256, 0, stream>>>(h1, W2, nsrc, g);
    gather_kernel<OC2, false><<<(NN + 3) / 4, 256, 0, stream>>>(g, ptr, esrc, ndst, b2, out);
}

// Round 3
// 257.677 us; speedup vs baseline: 2.5689x; 1.2675x over previous
//
#include <hip/hip_runtime.h>

#define NN 50000
#define NE 600000
#define KF 128      // IN_FEATS == H_FEATS
#define OC1 128
#define OC2 64
#define SCB 256
#define NSCB ((NN + SCB - 1) / SCB)   // 196

// ---------------- degree histogram (int atomics) ----------------
__global__ void deg_kernel(const int* __restrict__ src, const int* __restrict__ dst,
                           int* __restrict__ deg_o, int* __restrict__ deg_i) {
    int e = blockIdx.x * blockDim.x + threadIdx.x;
    if (e >= NE) return;
    atomicAdd(&deg_o[src[e]], 1);
    atomicAdd(&deg_i[dst[e]], 1);
}

// norms from integer degrees
__global__ void norm_kernel(const int* __restrict__ deg_o, const int* __restrict__ deg_i,
                            float* __restrict__ nsrc, float* __restrict__ ndst) {
    int i = blockIdx.x * blockDim.x + threadIdx.x;
    if (i >= NN) return;
    nsrc[i] = rsqrtf(fmaxf((float)deg_o[i], 1.0f));
    ndst[i] = rsqrtf(fmaxf((float)deg_i[i], 1.0f));
}

// ---------------- hierarchical exclusive scan of in-degrees -> col_ptr ----------------
// stage 1: per-block partial sums
__launch_bounds__(SCB)
__global__ void scan_part(const int* __restrict__ deg, int* __restrict__ bsum) {
    __shared__ int s[SCB];
    int i = blockIdx.x * SCB + threadIdx.x;
    s[threadIdx.x] = (i < NN) ? deg[i] : 0;
    __syncthreads();
    for (int off = SCB / 2; off > 0; off >>= 1) {
        if (threadIdx.x < off) s[threadIdx.x] += s[threadIdx.x + off];
        __syncthreads();
    }
    if (threadIdx.x == 0) bsum[blockIdx.x] = s[0];
}

// stage 2: exclusive scan of the NSCB block sums (single small block)
__launch_bounds__(SCB)
__global__ void scan_top(const int* __restrict__ bsum, int* __restrict__ boff) {
    __shared__ int s[SCB];
    const int tid = threadIdx.x;
    int v = (tid < NSCB) ? bsum[tid] : 0;
    s[tid] = v;
    __syncthreads();
    for (int off = 1; off < SCB; off <<= 1) {
        int t = (tid >= off) ? s[tid - off] : 0;
        __syncthreads();
        s[tid] += t;
        __syncthreads();
    }
    if (tid < NSCB) boff[tid] = s[tid] - v;   // exclusive
}

// stage 3: per-block exclusive scan + block offset -> ptr and cursor
__launch_bounds__(SCB)
__global__ void scan_fin(const int* __restrict__ deg, const int* __restrict__ boff,
                         int* __restrict__ ptr, int* __restrict__ cursor) {
    __shared__ int s[SCB];
    const int tid = threadIdx.x;
    int i = blockIdx.x * SCB + tid;
    int v = (i < NN) ? deg[i] : 0;
    s[tid] = v;
    __syncthreads();
    for (int off = 1; off < SCB; off <<= 1) {
        int t = (tid >= off) ? s[tid - off] : 0;
        __syncthreads();
        s[tid] += t;
        __syncthreads();
    }
    if (i < NN) {
        int e = boff[blockIdx.x] + s[tid] - v;
        ptr[i] = e;
        cursor[i] = e;
    }
    if (i == 0) ptr[NN] = NE;
}

// fill dst-sorted edge list
__global__ void fill_kernel(const int* __restrict__ src, const int* __restrict__ dst,
                            int* __restrict__ cursor, int* __restrict__ esrc) {
    int e = blockIdx.x * blockDim.x + threadIdx.x;
    if (e >= NE) return;
    int p = atomicAdd(&cursor[dst[e]], 1);
    esrc[p] = src[e];
}

// ---------------- GEMM: g[r] = nsrc[r] * (A[r] @ W) ----------------
// A: [NN, KF]  W: [KF, OC]  g: [NN, OC]
template <int OC>
__launch_bounds__(256)
__global__ void gemm_scale_kernel(const float* __restrict__ A, const float* __restrict__ W,
                                  const float* __restrict__ nsrc, float* __restrict__ g) {
    constexpr int CG = OC / 4;          // float4 column groups: 32 or 16
    constexpr int RT = 256 / CG;        // concurrent row-threads: 8 or 16
    constexpr int ROWS = 64;            // rows per block
    constexpr int RPT = ROWS / RT;      // rows per thread: 8 or 4
    constexpr int LDA4 = KF / 4 + 2;    // float4 stride 34 (544 B: 16B-aligned, +8-bank row shift)
    __shared__ float4 As[ROWS][LDA4];

    const int tid = threadIdx.x;
    const int row0 = blockIdx.x * ROWS;

    // cooperative float4 stage of the 64x128 A-tile
    for (int i = tid; i < ROWS * (KF / 4); i += 256) {
        int r = i >> 5;                 // KF/4 == 32
        int c = i & 31;
        float4 v = make_float4(0.f, 0.f, 0.f, 0.f);
        if (row0 + r < NN)
            v = reinterpret_cast<const float4*>(A + (size_t)(row0 + r) * KF)[c];
        As[r][c] = v;
    }
    __syncthreads();

    const int cg = tid % CG;
    const int rt = tid / CG;
    const float4* Wp = reinterpret_cast<const float4*>(W) + cg;

    float4 acc[RPT];
#pragma unroll
    for (int i = 0; i < RPT; i++) acc[i] = make_float4(0.f, 0.f, 0.f, 0.f);

#pragma unroll 4
    for (int k4 = 0; k4 < KF / 4; k4++) {
        float4 w0 = Wp[(4 * k4 + 0) * CG];
        float4 w1 = Wp[(4 * k4 + 1) * CG];
        float4 w2 = Wp[(4 * k4 + 2) * CG];
        float4 w3 = Wp[(4 * k4 + 3) * CG];
#pragma unroll
        for (int rr = 0; rr < RPT; rr++) {
            float4 a = As[rt + rr * RT][k4];
            acc[rr].x = fmaf(a.x, w0.x, acc[rr].x);
            acc[rr].y = fmaf(a.x, w0.y, acc[rr].y);
            acc[rr].z = fmaf(a.x, w0.z, acc[rr].z);
            acc[rr].w = fmaf(a.x, w0.w, acc[rr].w);
            acc[rr].x = fmaf(a.y, w1.x, acc[rr].x);
            acc[rr].y = fmaf(a.y, w1.y, acc[rr].y);
            acc[rr].z = fmaf(a.y, w1.z, acc[rr].z);
            acc[rr].w = fmaf(a.y, w1.w, acc[rr].w);
            acc[rr].x = fmaf(a.z, w2.x, acc[rr].x);
            acc[rr].y = fmaf(a.z, w2.y, acc[rr].y);
            acc[rr].z = fmaf(a.z, w2.z, acc[rr].z);
            acc[rr].w = fmaf(a.z, w2.w, acc[rr].w);
            acc[rr].x = fmaf(a.w, w3.x, acc[rr].x);
            acc[rr].y = fmaf(a.w, w3.y, acc[rr].y);
            acc[rr].z = fmaf(a.w, w3.z, acc[rr].z);
            acc[rr].w = fmaf(a.w, w3.w, acc[rr].w);
        }
    }

#pragma unroll
    for (int rr = 0; rr < RPT; rr++) {
        int r = row0 + rt + rr * RT;
        if (r < NN) {
            float ns = nsrc[r];
            float4 o = make_float4(acc[rr].x * ns, acc[rr].y * ns,
                                   acc[rr].z * ns, acc[rr].w * ns);
            reinterpret_cast<float4*>(g + (size_t)r * OC)[cg] = o;
        }
    }
}

// ---------------- gather: out[d] = act(ndst[d] * sum_{e in in(d)} g[esrc[e]] + b) ----------------
// one wave per node, block = 4 waves
template <int OC, bool RELU>
__launch_bounds__(256)
__global__ void gather_kernel(const float* __restrict__ g, const int* __restrict__ ptr,
                              const int* __restrict__ esrc, const float* __restrict__ ndst,
                              const float* __restrict__ b, float* __restrict__ out) {
    const int node = blockIdx.x * 4 + (threadIdx.x >> 6);
    if (node >= NN) return;
    const int lane = threadIdx.x & 63;
    const int lo = ptr[node];
    const int hi = ptr[node + 1];
    const float nd = ndst[node];

    if (OC == 128) {
        float2 acc0 = make_float2(0.f, 0.f), acc1 = make_float2(0.f, 0.f);
        int e = lo;
        for (; e + 1 < hi; e += 2) {
            int s0 = esrc[e];
            int s1 = esrc[e + 1];
            float2 v0 = reinterpret_cast<const float2*>(g + (size_t)s0 * OC)[lane];
            float2 v1 = reinterpret_cast<const float2*>(g + (size_t)s1 * OC)[lane];
            acc0.x += v0.x; acc0.y += v0.y;
            acc1.x += v1.x; acc1.y += v1.y;
        }
        if (e < hi) {
            int s0 = esrc[e];
            float2 v0 = reinterpret_cast<const float2*>(g + (size_t)s0 * OC)[lane];
            acc0.x += v0.x; acc0.y += v0.y;
        }
        acc0.x += acc1.x; acc0.y += acc1.y;
        float2 bb = reinterpret_cast<const float2*>(b)[lane];
        float2 o = make_float2(fmaf(acc0.x, nd, bb.x), fmaf(acc0.y, nd, bb.y));
        if (RELU) { o.x = fmaxf(o.x, 0.f); o.y = fmaxf(o.y, 0.f); }
        reinterpret_cast<float2*>(out + (size_t)node * OC)[lane] = o;
    } else {
        float acc0 = 0.f, acc1 = 0.f;
        int e = lo;
        for (; e + 1 < hi; e += 2) {
            int s0 = esrc[e];
            int s1 = esrc[e + 1];
            acc0 += g[(size_t)s0 * OC + lane];
            acc1 += g[(size_t)s1 * OC + lane];
        }
        if (e < hi) acc0 += g[(size_t)esrc[e] * OC + lane];
        acc0 += acc1;
        float o = fmaf(acc0, nd, b[lane]);
        if (RELU) o = fmaxf(o, 0.f);
        out[(size_t)node * OC + lane] = o;
    }
}

extern "C" void kernel_launch(void* const* d_in, const int* in_sizes, int n_in,
                              void* d_out, int out_size, void* d_ws, size_t ws_size,
                              hipStream_t stream) {
    const float* x  = (const float*)d_in[0];   // [NN, 128]
    const float* W1 = (const float*)d_in[1];   // [128, 128]
    const float* b1 = (const float*)d_in[2];   // [128]
    const float* W2 = (const float*)d_in[3];   // [128, 64]
    const float* b2 = (const float*)d_in[4];   // [64]
    const int*   src = (const int*)d_in[5];    // [NE]
    const int*   dst = (const int*)d_in[6];    // [NE]
    float* out = (float*)d_out;                // [NN, 64]

    float* ws   = (float*)d_ws;
    float* nsrc = ws;                          // NN
    float* ndst = nsrc + NN;                   // NN
    float* g    = ndst + NN;                   // NN*128 (layer 2 reuses as NN*64)
    float* h1   = g + (size_t)NN * KF;         // NN*128
    int*   deg_o  = (int*)(h1 + (size_t)NN * KF); // NN
    int*   deg_i  = deg_o + NN;                // NN
    int*   ptr    = deg_i + NN;                // NN+1
    int*   cursor = ptr + NN + 1;              // NN
    int*   esrc   = cursor + NN;               // NE
    int*   bsum   = esrc + NE;                 // NSCB
    int*   boff   = bsum + NSCB;               // NSCB

    // degrees -> norms, CSC build
    hipMemsetAsync(deg_o, 0, 2 * NN * sizeof(int), stream);
    deg_kernel<<<(NE + 255) / 256, 256, 0, stream>>>(src, dst, deg_o, deg_i);
    norm_kernel<<<(NN + 255) / 256, 256, 0, stream>>>(deg_o, deg_i, nsrc, ndst);
    scan_part<<<NSCB, SCB, 0, stream>>>(deg_i, bsum);
    scan_top<<<1, SCB, 0, stream>>>(bsum, boff);
    scan_fin<<<NSCB, SCB, 0, stream>>>(deg_i, boff, ptr, cursor);
    fill_kernel<<<(NE + 255) / 256, 256, 0, stream>>>(src, dst, cursor, esrc);

    // layer 1: g = nsrc * (x @ W1); h1 = relu(ndst * gather(g) + b1)
    gemm_scale_kernel<OC1><<<(NN + 63) / 64, 256, 0, stream>>>(x, W1, nsrc, g);
    gather_kernel<OC1, true><<<(NN + 3) / 4, 256, 0, stream>>>(g, ptr, esrc, ndst, b1, h1);

    // layer 2: g = nsrc * (h1 @ W2); out = ndst * gather(g) + b2
    gemm_scale_kernel<OC2><<<(NN + 63) / 64, 256, 0, stream>>>(h1, W2, nsrc, g);
    gather_kernel<OC2, false><<<(NN + 3) / 4, 256, 0, stream>>>(g, ptr, esrc, ndst, b2, out);
}

// Round 4
// 216.632 us; speedup vs baseline: 3.0557x; 1.1895x over previous
//
#include <hip/hip_runtime.h>
#include <hip/hip_fp16.h>

#define NN 50000
#define NE 600000
#define KF 128      // IN_FEATS == H_FEATS
#define OC1 128
#define OC2 64
#define SCB 256
#define NSCB ((NN + SCB - 1) / SCB)   // 196

// ---------------- degree histogram (int atomics) ----------------
__global__ void deg_kernel(const int* __restrict__ src, const int* __restrict__ dst,
                           int* __restrict__ deg_o, int* __restrict__ deg_i) {
    int e = blockIdx.x * blockDim.x + threadIdx.x;
    if (e >= NE) return;
    atomicAdd(&deg_o[src[e]], 1);
    atomicAdd(&deg_i[dst[e]], 1);
}

// norms from integer degrees
__global__ void norm_kernel(const int* __restrict__ deg_o, const int* __restrict__ deg_i,
                            float* __restrict__ nsrc, float* __restrict__ ndst) {
    int i = blockIdx.x * blockDim.x + threadIdx.x;
    if (i >= NN) return;
    nsrc[i] = rsqrtf(fmaxf((float)deg_o[i], 1.0f));
    ndst[i] = rsqrtf(fmaxf((float)deg_i[i], 1.0f));
}

// ---------------- hierarchical exclusive scan of in-degrees -> col_ptr ----------------
__launch_bounds__(SCB)
__global__ void scan_part(const int* __restrict__ deg, int* __restrict__ bsum) {
    __shared__ int s[SCB];
    int i = blockIdx.x * SCB + threadIdx.x;
    s[threadIdx.x] = (i < NN) ? deg[i] : 0;
    __syncthreads();
    for (int off = SCB / 2; off > 0; off >>= 1) {
        if (threadIdx.x < off) s[threadIdx.x] += s[threadIdx.x + off];
        __syncthreads();
    }
    if (threadIdx.x == 0) bsum[blockIdx.x] = s[0];
}

__launch_bounds__(SCB)
__global__ void scan_top(const int* __restrict__ bsum, int* __restrict__ boff) {
    __shared__ int s[SCB];
    const int tid = threadIdx.x;
    int v = (tid < NSCB) ? bsum[tid] : 0;
    s[tid] = v;
    __syncthreads();
    for (int off = 1; off < SCB; off <<= 1) {
        int t = (tid >= off) ? s[tid - off] : 0;
        __syncthreads();
        s[tid] += t;
        __syncthreads();
    }
    if (tid < NSCB) boff[tid] = s[tid] - v;   // exclusive
}

__launch_bounds__(SCB)
__global__ void scan_fin(const int* __restrict__ deg, const int* __restrict__ boff,
                         int* __restrict__ ptr, int* __restrict__ cursor) {
    __shared__ int s[SCB];
    const int tid = threadIdx.x;
    int i = blockIdx.x * SCB + tid;
    int v = (i < NN) ? deg[i] : 0;
    s[tid] = v;
    __syncthreads();
    for (int off = 1; off < SCB; off <<= 1) {
        int t = (tid >= off) ? s[tid - off] : 0;
        __syncthreads();
        s[tid] += t;
        __syncthreads();
    }
    if (i < NN) {
        int e = boff[blockIdx.x] + s[tid] - v;
        ptr[i] = e;
        cursor[i] = e;
    }
    if (i == 0) ptr[NN] = NE;
}

// fill dst-sorted edge list
__global__ void fill_kernel(const int* __restrict__ src, const int* __restrict__ dst,
                            int* __restrict__ cursor, int* __restrict__ esrc) {
    int e = blockIdx.x * blockDim.x + threadIdx.x;
    if (e >= NE) return;
    int p = atomicAdd(&cursor[dst[e]], 1);
    esrc[p] = src[e];
}

// ---------------- GEMM: g[r] = fp16( nsrc[r] * (A[r] @ W) ) ----------------
// A: [NN, KF] (f32 or f16)  W: [KF, OC] f32  g: [NN, OC] f16
template <int OC, typename AT>
__launch_bounds__(256)
__global__ void gemm_scale_kernel(const AT* __restrict__ A, const float* __restrict__ W,
                                  const float* __restrict__ nsrc, __half* __restrict__ g) {
    constexpr int CG = OC / 4;          // float4 column groups: 32 or 16
    constexpr int RT = 256 / CG;        // concurrent row-threads: 8 or 16
    constexpr int ROWS = 64;            // rows per block
    constexpr int RPT = ROWS / RT;      // rows per thread: 8 or 4
    constexpr int LDA4 = KF / 4 + 2;    // float4 stride 34: 16B-aligned, rows shift 8 banks
    __shared__ float4 As[ROWS][LDA4];

    const int tid = threadIdx.x;
    const int row0 = blockIdx.x * ROWS;

    // cooperative stage of the 64x128 A-tile (convert fp16 -> f32 if needed)
    for (int i = tid; i < ROWS * (KF / 4); i += 256) {
        int r = i >> 5;                 // KF/4 == 32
        int c = i & 31;
        float4 v = make_float4(0.f, 0.f, 0.f, 0.f);
        if (row0 + r < NN) {
            if constexpr (sizeof(AT) == 4) {
                v = reinterpret_cast<const float4*>(A + (size_t)(row0 + r) * KF)[c];
            } else {
                uint2 u = reinterpret_cast<const uint2*>(A + (size_t)(row0 + r) * KF)[c];
                __half2 ha = *reinterpret_cast<__half2*>(&u.x);
                __half2 hb = *reinterpret_cast<__half2*>(&u.y);
                float2 fa = __half22float2(ha);
                float2 fb = __half22float2(hb);
                v = make_float4(fa.x, fa.y, fb.x, fb.y);
            }
        }
        As[r][c] = v;
    }
    __syncthreads();

    const int cg = tid % CG;
    const int rt = tid / CG;
    const float4* Wp = reinterpret_cast<const float4*>(W) + cg;

    float4 acc[RPT];
#pragma unroll
    for (int i = 0; i < RPT; i++) acc[i] = make_float4(0.f, 0.f, 0.f, 0.f);

#pragma unroll 4
    for (int k4 = 0; k4 < KF / 4; k4++) {
        float4 w0 = Wp[(4 * k4 + 0) * CG];
        float4 w1 = Wp[(4 * k4 + 1) * CG];
        float4 w2 = Wp[(4 * k4 + 2) * CG];
        float4 w3 = Wp[(4 * k4 + 3) * CG];
#pragma unroll
        for (int rr = 0; rr < RPT; rr++) {
            float4 a = As[rt + rr * RT][k4];
            acc[rr].x = fmaf(a.x, w0.x, acc[rr].x);
            acc[rr].y = fmaf(a.x, w0.y, acc[rr].y);
            acc[rr].z = fmaf(a.x, w0.z, acc[rr].z);
            acc[rr].w = fmaf(a.x, w0.w, acc[rr].w);
            acc[rr].x = fmaf(a.y, w1.x, acc[rr].x);
            acc[rr].y = fmaf(a.y, w1.y, acc[rr].y);
            acc[rr].z = fmaf(a.y, w1.z, acc[rr].z);
            acc[rr].w = fmaf(a.y, w1.w, acc[rr].w);
            acc[rr].x = fmaf(a.z, w2.x, acc[rr].x);
            acc[rr].y = fmaf(a.z, w2.y, acc[rr].y);
            acc[rr].z = fmaf(a.z, w2.z, acc[rr].z);
            acc[rr].w = fmaf(a.z, w2.w, acc[rr].w);
            acc[rr].x = fmaf(a.w, w3.x, acc[rr].x);
            acc[rr].y = fmaf(a.w, w3.y, acc[rr].y);
            acc[rr].z = fmaf(a.w, w3.z, acc[rr].z);
            acc[rr].w = fmaf(a.w, w3.w, acc[rr].w);
        }
    }

#pragma unroll
    for (int rr = 0; rr < RPT; rr++) {
        int r = row0 + rt + rr * RT;
        if (r < NN) {
            float ns = nsrc[r];
            __half2 lo = __floats2half2_rn(acc[rr].x * ns, acc[rr].y * ns);
            __half2 hi = __floats2half2_rn(acc[rr].z * ns, acc[rr].w * ns);
            uint2 pk;
            pk.x = *reinterpret_cast<unsigned int*>(&lo);
            pk.y = *reinterpret_cast<unsigned int*>(&hi);
            reinterpret_cast<uint2*>(g + (size_t)r * OC)[cg] = pk;
        }
    }
}

// ---------------- gather (OC=128): h1[d] = fp16(relu(ndst*sum g[esrc] + b)) ----------------
// one wave per node, lane owns 2 feats (half2), 4-edge unroll
__launch_bounds__(256)
__global__ void gather128_kernel(const __half2* __restrict__ g, const int* __restrict__ ptr,
                                 const int* __restrict__ esrc, const float* __restrict__ ndst,
                                 const float* __restrict__ b, __half2* __restrict__ h1) {
    const int node = blockIdx.x * 4 + (threadIdx.x >> 6);
    if (node >= NN) return;
    const int lane = threadIdx.x & 63;
    const int lo = ptr[node];
    const int hi = ptr[node + 1];
    const float nd = ndst[node];

    float2 a0 = make_float2(0.f, 0.f), a1 = a0, a2 = a0, a3 = a0;
    int e = lo;
    for (; e + 3 < hi; e += 4) {
        int s0 = esrc[e], s1 = esrc[e + 1], s2 = esrc[e + 2], s3 = esrc[e + 3];
        float2 v0 = __half22float2(g[(size_t)s0 * 64 + lane]);
        float2 v1 = __half22float2(g[(size_t)s1 * 64 + lane]);
        float2 v2 = __half22float2(g[(size_t)s2 * 64 + lane]);
        float2 v3 = __half22float2(g[(size_t)s3 * 64 + lane]);
        a0.x += v0.x; a0.y += v0.y;
        a1.x += v1.x; a1.y += v1.y;
        a2.x += v2.x; a2.y += v2.y;
        a3.x += v3.x; a3.y += v3.y;
    }
    for (; e < hi; e++) {
        float2 v = __half22float2(g[(size_t)esrc[e] * 64 + lane]);
        a0.x += v.x; a0.y += v.y;
    }
    a0.x += a1.x + a2.x + a3.x;
    a0.y += a1.y + a2.y + a3.y;
    float2 bb = reinterpret_cast<const float2*>(b)[lane];
    float ox = fmaxf(fmaf(a0.x, nd, bb.x), 0.f);
    float oy = fmaxf(fmaf(a0.y, nd, bb.y), 0.f);
    h1[(size_t)node * 64 + lane] = __floats2half2_rn(ox, oy);
}

// ---------------- gather (OC=64): out[d] = f32(ndst*sum g[esrc] + b) ----------------
// one wave per node; half-wave per edge (lane&31 owns 2 feats), 2x unroll per half
__launch_bounds__(256)
__global__ void gather64_kernel(const __half2* __restrict__ g, const int* __restrict__ ptr,
                                const int* __restrict__ esrc, const float* __restrict__ ndst,
                                const float* __restrict__ b, float* __restrict__ out) {
    const int node = blockIdx.x * 4 + (threadIdx.x >> 6);
    if (node >= NN) return;
    const int lane = threadIdx.x & 63;
    const int l32 = lane & 31;
    const int half_id = lane >> 5;
    const int lo = ptr[node];
    const int hi = ptr[node + 1];
    const float nd = ndst[node];

    float2 a0 = make_float2(0.f, 0.f), a1 = a0;
    int e = lo + half_id;
    for (; e + 2 < hi; e += 4) {
        int s0 = esrc[e], s1 = esrc[e + 2];
        float2 v0 = __half22float2(g[(size_t)s0 * 32 + l32]);
        float2 v1 = __half22float2(g[(size_t)s1 * 32 + l32]);
        a0.x += v0.x; a0.y += v0.y;
        a1.x += v1.x; a1.y += v1.y;
    }
    if (e < hi) {
        float2 v = __half22float2(g[(size_t)esrc[e] * 32 + l32]);
        a0.x += v.x; a0.y += v.y;
    }
    a0.x += a1.x;
    a0.y += a1.y;
    // combine the two half-wave partial sums
    a0.x += __shfl_xor(a0.x, 32);
    a0.y += __shfl_xor(a0.y, 32);
    if (half_id == 0) {
        float2 bb = reinterpret_cast<const float2*>(b)[l32];
        float2 o = make_float2(fmaf(a0.x, nd, bb.x), fmaf(a0.y, nd, bb.y));
        reinterpret_cast<float2*>(out + (size_t)node * 64)[l32] = o;
    }
}

extern "C" void kernel_launch(void* const* d_in, const int* in_sizes, int n_in,
                              void* d_out, int out_size, void* d_ws, size_t ws_size,
                              hipStream_t stream) {
    const float* x  = (const float*)d_in[0];   // [NN, 128]
    const float* W1 = (const float*)d_in[1];   // [128, 128]
    const float* b1 = (const float*)d_in[2];   // [128]
    const float* W2 = (const float*)d_in[3];   // [128, 64]
    const float* b2 = (const float*)d_in[4];   // [64]
    const int*   src = (const int*)d_in[5];    // [NE]
    const int*   dst = (const int*)d_in[6];    // [NE]
    float* out = (float*)d_out;                // [NN, 64]

    float*  nsrc = (float*)d_ws;                     // NN
    float*  ndst = nsrc + NN;                        // NN
    __half* g    = (__half*)(ndst + NN);             // NN*128 f16 (layer 2 uses NN*64)
    __half* h1   = g + (size_t)NN * KF;              // NN*128 f16
    int* deg_o  = (int*)(h1 + (size_t)NN * KF);      // NN
    int* deg_i  = deg_o + NN;                        // NN
    int* ptr    = deg_i + NN;                        // NN+1
    int* cursor = ptr + NN + 1;                      // NN
    int* esrc   = cursor + NN;                       // NE
    int* bsum   = esrc + NE;                         // NSCB
    int* boff   = bsum + NSCB;                       // NSCB

    // degrees -> norms, CSC build
    hipMemsetAsync(deg_o, 0, 2 * NN * sizeof(int), stream);
    deg_kernel<<<(NE + 255) / 256, 256, 0, stream>>>(src, dst, deg_o, deg_i);
    norm_kernel<<<(NN + 255) / 256, 256, 0, stream>>>(deg_o, deg_i, nsrc, ndst);
    scan_part<<<NSCB, SCB, 0, stream>>>(deg_i, bsum);
    scan_top<<<1, SCB, 0, stream>>>(bsum, boff);
    scan_fin<<<NSCB, SCB, 0, stream>>>(deg_i, boff, ptr, cursor);
    fill_kernel<<<(NE + 255) / 256, 256, 0, stream>>>(src, dst, cursor, esrc);

    // layer 1: g = fp16(nsrc * (x @ W1)); h1 = fp16(relu(ndst * gather(g) + b1))
    gemm_scale_kernel<OC1, float><<<(NN + 63) / 64, 256, 0, stream>>>(x, W1, nsrc, g);
    gather128_kernel<<<(NN + 3) / 4, 256, 0, stream>>>((const __half2*)g, ptr, esrc, ndst, b1,
                                                       (__half2*)h1);

    // layer 2: g = fp16(nsrc * (h1 @ W2)); out = ndst * gather(g) + b2
    gemm_scale_kernel<OC2, __half><<<(NN + 63) / 64, 256, 0, stream>>>(h1, W2, nsrc, g);
    gather64_kernel<<<(NN + 3) / 4, 256, 0, stream>>>((const __half2*)g, ptr, esrc, ndst, b2, out);
}